// Round 1
// baseline (479.191 us; speedup 1.0000x reference)
//
#include <hip/hip_runtime.h>
#include <hip/hip_bf16.h>

#define NB 4
#define SLEN 2048
#define DMODEL 1024
#define NH 16
#define DH 64

using f32x4  = __attribute__((ext_vector_type(4))) float;
using bf16x8 = __attribute__((ext_vector_type(8))) short;

__device__ __forceinline__ unsigned short f2bf(float f) {
    unsigned int u = __float_as_uint(f);
    u += 0x7FFFu + ((u >> 16) & 1u);   // round-to-nearest-even
    return (unsigned short)(u >> 16);
}

// ---------------------------------------------------------------------------
// Kernel 1: per-head QKV projection.
//   Q[nh][s][e] = (X_h[s][:] . Wq_h[:,e] + bq) * 0.125   (1/sqrt(DH) folded in)
//   K[nh][s][e] =  X_h[s][:] . Wk_h[:,e] + bk
//   Vt[nh][e][s] = X_h[s][:] . Wv_h[:,e] + bv            (stored transposed)
// Block: 256 threads (4 waves), handles 64 seq rows for one (n,h).
// ---------------------------------------------------------------------------
__global__ __launch_bounds__(256) void qkv_proj_kernel(
    const float* __restrict__ seq,
    const float* __restrict__ Wq, const float* __restrict__ bq,
    const float* __restrict__ Wk, const float* __restrict__ bk,
    const float* __restrict__ Wv, const float* __restrict__ bv,
    unsigned short* __restrict__ Qb,
    unsigned short* __restrict__ Kb,
    unsigned short* __restrict__ Vt)
{
    const int bid  = blockIdx.x;
    const int nh   = bid >> 5;      // 32 row-tiles per (n,h)
    const int tile = bid & 31;
    const int n = nh >> 4, h = nh & 15;
    const int t0 = tile * 64;
    const int tid = threadIdx.x;
    const int w  = tid >> 6;
    const int l  = tid & 63;
    const int g  = l >> 4;
    const int ln = l & 15;

    // W transposed into LDS: wt[p][e*72 + d]  (pad 72 -> 16B-aligned rows)
    __shared__ unsigned short wt[3][64 * 72];

    {
        const float* Wsrc0 = Wq + h * 4096;
        const float* Wsrc1 = Wk + h * 4096;
        const float* Wsrc2 = Wv + h * 4096;
        for (int idx = tid; idx < 4096; idx += 256) {
            int d = idx >> 6, e = idx & 63;
            wt[0][e * 72 + d] = f2bf(Wsrc0[idx]);
            wt[1][e * 72 + d] = f2bf(Wsrc1[idx]);
            wt[2][e * 72 + d] = f2bf(Wsrc2[idx]);
        }
    }
    __syncthreads();

    // A fragments: X rows of this wave's 16-row strip (lane ln = row, g = k-chunk)
    const float* xrow = seq + ((size_t)(n * SLEN + t0 + w * 16 + ln)) * DMODEL + h * DH;
    bf16x8 a[2];
#pragma unroll
    for (int kk = 0; kk < 2; ++kk) {
        const float4* src = reinterpret_cast<const float4*>(xrow + kk * 32 + g * 8);
        float4 v0 = src[0];
        float4 v1 = src[1];
        bf16x8 av;
        av[0] = (short)f2bf(v0.x); av[1] = (short)f2bf(v0.y);
        av[2] = (short)f2bf(v0.z); av[3] = (short)f2bf(v0.w);
        av[4] = (short)f2bf(v1.x); av[5] = (short)f2bf(v1.y);
        av[6] = (short)f2bf(v1.z); av[7] = (short)f2bf(v1.w);
        a[kk] = av;
    }

    const float* bias0 = bq + h * DH;
    const float* bias1 = bk + h * DH;
    const float* bias2 = bv + h * DH;

#pragma unroll
    for (int p = 0; p < 3; ++p) {
#pragma unroll
        for (int cb = 0; cb < 4; ++cb) {
            f32x4 acc = {0.f, 0.f, 0.f, 0.f};
#pragma unroll
            for (int kk = 0; kk < 2; ++kk) {
                bf16x8 b = *reinterpret_cast<bf16x8*>(
                    &wt[p][(cb * 16 + ln) * 72 + kk * 32 + g * 8]);
                acc = __builtin_amdgcn_mfma_f32_16x16x32_bf16(a[kk], b, acc, 0, 0, 0);
            }
            const int col = cb * 16 + ln;
            if (p == 0) {
                const float bb = bias0[col];
                // rows m = g*4 + r ; global s = t0 + w*16 + m
#pragma unroll
                for (int r = 0; r < 4; ++r) {
                    float qv = (acc[r] + bb) * 0.125f;
                    Qb[((size_t)(nh * SLEN + t0 + w * 16 + g * 4 + r)) * DH + col] = f2bf(qv);
                }
            } else if (p == 1) {
                const float bb = bias1[col];
#pragma unroll
                for (int r = 0; r < 4; ++r) {
                    Kb[((size_t)(nh * SLEN + t0 + w * 16 + g * 4 + r)) * DH + col] =
                        f2bf(acc[r] + bb);
                }
            } else {
                const float bb = bias2[col];
                ushort4 pack;
                pack.x = f2bf(acc[0] + bb);
                pack.y = f2bf(acc[1] + bb);
                pack.z = f2bf(acc[2] + bb);
                pack.w = f2bf(acc[3] + bb);
                // Vt[(nh*64 + e) * SLEN + s], 4 consecutive s -> one 8B store
                *reinterpret_cast<ushort4*>(
                    &Vt[((size_t)(nh * 64 + col)) * SLEN + t0 + w * 16 + g * 4]) = pack;
            }
        }
    }
}

// ---------------------------------------------------------------------------
// Kernel 2: flash attention. Block = one (n,h,64-row q-tile), 4 waves,
// each wave owns a 16-row q strip. KV tiles of 64, online softmax.
// ---------------------------------------------------------------------------
__global__ __launch_bounds__(256) void attn_kernel(
    const unsigned short* __restrict__ Qb,
    const unsigned short* __restrict__ Kb,
    const unsigned short* __restrict__ Vt,
    float* __restrict__ out)
{
    const int bid = blockIdx.x;
    const int nh  = bid >> 5;
    const int qt  = bid & 31;
    const int n = nh >> 4, h = nh & 15;
    const int q0 = qt * 64;
    const int tid = threadIdx.x;
    const int w  = tid >> 6;
    const int l  = tid & 63;
    const int g  = l >> 4;
    const int ln = l & 15;

    __shared__ unsigned short p_lds[4][16 * 72];   // per-wave P buffer, padded

    // Q fragments (already scaled by 1/8)
    const unsigned short* qrow = Qb + ((size_t)(nh * SLEN + q0 + w * 16 + ln)) * DH;
    bf16x8 aq0 = *reinterpret_cast<const bf16x8*>(qrow + g * 8);
    bf16x8 aq1 = *reinterpret_cast<const bf16x8*>(qrow + 32 + g * 8);

    f32x4 o[4];
#pragma unroll
    for (int cb = 0; cb < 4; ++cb) { o[cb][0]=0.f; o[cb][1]=0.f; o[cb][2]=0.f; o[cb][3]=0.f; }
    float m_old[4] = {-3e38f, -3e38f, -3e38f, -3e38f};
    float l_row[4] = {0.f, 0.f, 0.f, 0.f};

    const unsigned short* Kbase = Kb + (size_t)nh * SLEN * DH;
    const unsigned short* Vbase = Vt + (size_t)nh * DH * SLEN;
    unsigned short* pw = &p_lds[w][0];

    for (int kt = 0; kt < SLEN; kt += 64) {
        // ---- QK^T ----
        f32x4 sc[4];
#pragma unroll
        for (int cb = 0; cb < 4; ++cb) {
            f32x4 acc = {0.f, 0.f, 0.f, 0.f};
            const unsigned short* krow = Kbase + (size_t)(kt + cb * 16 + ln) * DH + g * 8;
            bf16x8 b0 = *reinterpret_cast<const bf16x8*>(krow);
            bf16x8 b1 = *reinterpret_cast<const bf16x8*>(krow + 32);
            acc = __builtin_amdgcn_mfma_f32_16x16x32_bf16(aq0, b0, acc, 0, 0, 0);
            acc = __builtin_amdgcn_mfma_f32_16x16x32_bf16(aq1, b1, acc, 0, 0, 0);
            sc[cb] = acc;
        }

        // ---- online softmax (rows m = g*4 + r live in 16-lane groups) ----
        float corr[4];
#pragma unroll
        for (int r = 0; r < 4; ++r) {
            float mx = fmaxf(fmaxf(sc[0][r], sc[1][r]), fmaxf(sc[2][r], sc[3][r]));
#pragma unroll
            for (int ofs = 1; ofs < 16; ofs <<= 1)
                mx = fmaxf(mx, __shfl_xor(mx, ofs));
            float mn = fmaxf(m_old[r], mx);
            corr[r] = __expf(m_old[r] - mn);
            m_old[r] = mn;
        }
        float rowsum[4] = {0.f, 0.f, 0.f, 0.f};
#pragma unroll
        for (int cb = 0; cb < 4; ++cb) {
#pragma unroll
            for (int r = 0; r < 4; ++r) {
                float p = __expf(sc[cb][r] - m_old[r]);
                sc[cb][r] = p;
                rowsum[r] += p;
            }
        }
#pragma unroll
        for (int r = 0; r < 4; ++r) {
#pragma unroll
            for (int ofs = 1; ofs < 16; ofs <<= 1)
                rowsum[r] += __shfl_xor(rowsum[r], ofs);
            l_row[r] = l_row[r] * corr[r] + rowsum[r];
            o[0][r] *= corr[r];
            o[1][r] *= corr[r];
            o[2][r] *= corr[r];
            o[3][r] *= corr[r];
        }

        // ---- P (D-layout) -> LDS -> A-layout (same-wave only, no barrier) ----
#pragma unroll
        for (int cb = 0; cb < 4; ++cb)
#pragma unroll
            for (int r = 0; r < 4; ++r)
                pw[(g * 4 + r) * 72 + cb * 16 + ln] = f2bf(sc[cb][r]);

        bf16x8 ap0 = *reinterpret_cast<bf16x8*>(&pw[ln * 72 + g * 8]);
        bf16x8 ap1 = *reinterpret_cast<bf16x8*>(&pw[ln * 72 + 32 + g * 8]);

        // ---- PV ----
#pragma unroll
        for (int cb = 0; cb < 4; ++cb) {
            const unsigned short* vrow = Vbase + (size_t)(cb * 16 + ln) * SLEN + kt + g * 8;
            bf16x8 b0 = *reinterpret_cast<const bf16x8*>(vrow);
            bf16x8 b1 = *reinterpret_cast<const bf16x8*>(vrow + 32);
            o[cb] = __builtin_amdgcn_mfma_f32_16x16x32_bf16(ap0, b0, o[cb], 0, 0, 0);
            o[cb] = __builtin_amdgcn_mfma_f32_16x16x32_bf16(ap1, b1, o[cb], 0, 0, 0);
        }
    }

    // ---- epilogue: normalize and store fp32 ----
#pragma unroll
    for (int r = 0; r < 4; ++r) {
        float inv = 1.0f / l_row[r];
        int srow = q0 + w * 16 + g * 4 + r;
        float* dst = out + ((size_t)(n * SLEN + srow)) * DMODEL + h * DH;
#pragma unroll
        for (int cb = 0; cb < 4; ++cb)
            dst[cb * 16 + ln] = o[cb][r] * inv;
    }
}

extern "C" void kernel_launch(void* const* d_in, const int* in_sizes, int n_in,
                              void* d_out, int out_size, void* d_ws, size_t ws_size,
                              hipStream_t stream) {
    const float* seq = (const float*)d_in[0];
    const float* Wq  = (const float*)d_in[1];
    const float* bq  = (const float*)d_in[2];
    const float* Wk  = (const float*)d_in[3];
    const float* bk  = (const float*)d_in[4];
    const float* Wv  = (const float*)d_in[5];
    const float* bv  = (const float*)d_in[6];

    const size_t per_tensor = (size_t)NB * NH * SLEN * DH;   // 8.39M bf16 elems
    unsigned short* Qb = (unsigned short*)d_ws;
    unsigned short* Kb = Qb + per_tensor;
    unsigned short* Vt = Kb + per_tensor;

    const int blocks = NB * NH * (SLEN / 64);   // 2048

    qkv_proj_kernel<<<dim3(blocks), dim3(256), 0, stream>>>(
        seq, Wq, bq, Wk, bk, Wv, bv, Qb, Kb, Vt);
    attn_kernel<<<dim3(blocks), dim3(256), 0, stream>>>(
        Qb, Kb, Vt, (float*)d_out);
}

// Round 3
// 259.025 us; speedup vs baseline: 1.8500x; 1.8500x over previous
//
#include <hip/hip_runtime.h>
#include <hip/hip_bf16.h>

#define NB 4
#define SLEN 2048
#define DMODEL 1024
#define NH 16
#define DH 64

using f32x4  = __attribute__((ext_vector_type(4))) float;
using f32x16 = __attribute__((ext_vector_type(16))) float;
using bf16x8 = __attribute__((ext_vector_type(8))) short;
using u32x4  = __attribute__((ext_vector_type(4))) unsigned int;

__device__ __forceinline__ unsigned short f2bf(float f) {
    unsigned int u = __float_as_uint(f);
    u += 0x7FFFu + ((u >> 16) & 1u);   // round-to-nearest-even
    return (unsigned short)(u >> 16);
}

__device__ __forceinline__ float fast_exp2(float x) {
    float r;
    asm("v_exp_f32 %0, %1" : "=v"(r) : "v"(x));   // D = 2^S0 (ISA §3)
    return r;
}

__device__ __forceinline__ unsigned cvtpk(float lo, float hi) {
    unsigned r;
    asm("v_cvt_pk_bf16_f32 %0, %1, %2" : "=v"(r) : "v"(lo), "v"(hi));
    return r;
}

__device__ __forceinline__ void permswap(unsigned& a, unsigned& b) {
    // a' = {a.lo32lanes, b.lo32lanes}, b' = {a.hi32lanes, b.hi32lanes}
    asm("v_permlane32_swap_b32 %0, %1" : "+v"(a), "+v"(b));
}

// 0.125 (1/sqrt(DH)) * log2(e): softmax computed in exp2 domain
#define QSCALE 0.18033688011112042f

// ---------------------------------------------------------------------------
// Kernel 1: per-head QKV projection.
//   Q[nh][s][e] = (X_h . Wq + bq) * QSCALE      (bf16, row-major)
//   K[nh][s][e] =  X_h . Wk + bk                (bf16, row-major)
//   Vt[nh][e][s] = X_h . Wv + bv                (bf16, transposed)
// ---------------------------------------------------------------------------
__global__ __launch_bounds__(256) void qkv_proj_kernel(
    const float* __restrict__ seq,
    const float* __restrict__ Wq, const float* __restrict__ bq,
    const float* __restrict__ Wk, const float* __restrict__ bk,
    const float* __restrict__ Wv, const float* __restrict__ bv,
    unsigned short* __restrict__ Qb,
    unsigned short* __restrict__ Kb,
    unsigned short* __restrict__ Vt)
{
    const int bid  = blockIdx.x;
    const int nh   = bid >> 5;
    const int tile = bid & 31;
    const int h = nh & 15;
    const int n = nh >> 4;
    const int t0 = tile * 64;
    const int tid = threadIdx.x;
    const int w  = tid >> 6;
    const int l  = tid & 63;
    const int g  = l >> 4;
    const int ln = l & 15;

    __shared__ unsigned short wt[3][64 * 72];

    {
        const float* Wsrc0 = Wq + h * 4096;
        const float* Wsrc1 = Wk + h * 4096;
        const float* Wsrc2 = Wv + h * 4096;
        for (int idx = tid; idx < 4096; idx += 256) {
            int d = idx >> 6, e = idx & 63;
            wt[0][e * 72 + d] = f2bf(Wsrc0[idx]);
            wt[1][e * 72 + d] = f2bf(Wsrc1[idx]);
            wt[2][e * 72 + d] = f2bf(Wsrc2[idx]);
        }
    }
    __syncthreads();

    const float* xrow = seq + ((size_t)(n * SLEN + t0 + w * 16 + ln)) * DMODEL + h * DH;
    bf16x8 a[2];
#pragma unroll
    for (int kk = 0; kk < 2; ++kk) {
        const float4* src = reinterpret_cast<const float4*>(xrow + kk * 32 + g * 8);
        float4 v0 = src[0];
        float4 v1 = src[1];
        bf16x8 av;
        av[0] = (short)f2bf(v0.x); av[1] = (short)f2bf(v0.y);
        av[2] = (short)f2bf(v0.z); av[3] = (short)f2bf(v0.w);
        av[4] = (short)f2bf(v1.x); av[5] = (short)f2bf(v1.y);
        av[6] = (short)f2bf(v1.z); av[7] = (short)f2bf(v1.w);
        a[kk] = av;
    }

    const float* bias0 = bq + h * DH;
    const float* bias1 = bk + h * DH;
    const float* bias2 = bv + h * DH;

#pragma unroll
    for (int p = 0; p < 3; ++p) {
#pragma unroll
        for (int cb = 0; cb < 4; ++cb) {
            f32x4 acc = {0.f, 0.f, 0.f, 0.f};
#pragma unroll
            for (int kk = 0; kk < 2; ++kk) {
                bf16x8 b = *reinterpret_cast<bf16x8*>(
                    &wt[p][(cb * 16 + ln) * 72 + kk * 32 + g * 8]);
                acc = __builtin_amdgcn_mfma_f32_16x16x32_bf16(a[kk], b, acc, 0, 0, 0);
            }
            const int col = cb * 16 + ln;
            if (p == 0) {
                const float bb = bias0[col];
#pragma unroll
                for (int r = 0; r < 4; ++r) {
                    float qv = (acc[r] + bb) * QSCALE;
                    Qb[((size_t)(nh * SLEN + t0 + w * 16 + g * 4 + r)) * DH + col] = f2bf(qv);
                }
            } else if (p == 1) {
                const float bb = bias1[col];
#pragma unroll
                for (int r = 0; r < 4; ++r) {
                    Kb[((size_t)(nh * SLEN + t0 + w * 16 + g * 4 + r)) * DH + col] =
                        f2bf(acc[r] + bb);
                }
            } else {
                const float bb = bias2[col];
                ushort4 pack;
                pack.x = f2bf(acc[0] + bb);
                pack.y = f2bf(acc[1] + bb);
                pack.z = f2bf(acc[2] + bb);
                pack.w = f2bf(acc[3] + bb);
                *reinterpret_cast<ushort4*>(
                    &Vt[((size_t)(nh * 64 + col)) * SLEN + t0 + w * 16 + g * 4]) = pack;
            }
        }
    }
}

// ---------------------------------------------------------------------------
// Kernel 2: flash attention, swapped-operand 32x32x16 structure.
// Block = 4 independent waves, each owns 32 q-rows. No LDS, no barriers.
//   QK^T:  S^T[k][q] = mfma(A=K, B=Q^T)  -> lane holds 32 scores of q=lane&31
//   PV:    O[q][d]   = mfma(A=V^T, B=P^T) -> col=lane&31=q, rows=d
// Softmax fully in-register; P->bf16 A-frags via cvt_pk + permlane32_swap.
// ---------------------------------------------------------------------------
__global__ __launch_bounds__(256) void attn_kernel(
    const unsigned short* __restrict__ Qb,
    const unsigned short* __restrict__ Kb,
    const unsigned short* __restrict__ Vt,
    float* __restrict__ out)
{
    const int bid = blockIdx.x;
    // XCD-chunked swizzle (1024 blocks % 8 == 0 -> bijective):
    // co-locates each head's 16 q-tile blocks on one XCD for K/V L2 reuse.
    const int swz = (bid & 7) * 128 + (bid >> 3);
    const int nh = swz >> 4;
    const int qt = swz & 15;
    const int n = nh >> 4, h = nh & 15;
    const int tid = threadIdx.x;
    const int w  = tid >> 6;
    const int l  = tid & 63;
    const int lq = l & 31;          // this lane's q column
    const int hi = l >> 5;
    const int q0 = qt * 128 + w * 32;

    // Q fragments (B-operand: col=q=lane&31, k-dim rows = hi*8+j), 4 k-steps
    const unsigned short* qrow = Qb + ((size_t)(nh * SLEN + q0 + lq)) * DH + hi * 8;
    bf16x8 qf[4];
#pragma unroll
    for (int ks = 0; ks < 4; ++ks)
        qf[ks] = *reinterpret_cast<const bf16x8*>(qrow + ks * 16);

    const unsigned short* Kbase = Kb + (size_t)nh * SLEN * DH;
    const unsigned short* Vbase = Vt + (size_t)nh * DH * SLEN;

    f32x16 oA, oB;
#pragma unroll
    for (int r = 0; r < 16; ++r) { oA[r] = 0.f; oB[r] = 0.f; }
    float m_run = -3.0e38f;
    float l_run = 0.f;

    for (int kt = 0; kt < SLEN; kt += 64) {
        // ---- QK^T (swapped): A = K rows, B = Q^T ----
        const unsigned short* ka0 = Kbase + ((size_t)(kt + lq)) * DH + hi * 8;
        const unsigned short* ka1 = ka0 + 32 * DH;
        f32x16 s0, s1;
#pragma unroll
        for (int r = 0; r < 16; ++r) { s0[r] = 0.f; s1[r] = 0.f; }
        {
            bf16x8 kf[4];
#pragma unroll
            for (int ks = 0; ks < 4; ++ks)
                kf[ks] = *reinterpret_cast<const bf16x8*>(ka0 + ks * 16);
#pragma unroll
            for (int ks = 0; ks < 4; ++ks)
                s0 = __builtin_amdgcn_mfma_f32_32x32x16_bf16(kf[ks], qf[ks], s0, 0, 0, 0);
#pragma unroll
            for (int ks = 0; ks < 4; ++ks)
                kf[ks] = *reinterpret_cast<const bf16x8*>(ka1 + ks * 16);
#pragma unroll
            for (int ks = 0; ks < 4; ++ks)
                s1 = __builtin_amdgcn_mfma_f32_32x32x16_bf16(kf[ks], qf[ks], s1, 0, 0, 0);
        }

        // ---- V^T fragments for PV (issue loads early; latency hides under softmax)
        bf16x8 vf[2][4];
#pragma unroll
        for (int hh = 0; hh < 2; ++hh)
#pragma unroll
            for (int f = 0; f < 4; ++f)
                vf[hh][f] = *reinterpret_cast<const bf16x8*>(
                    Vbase + ((size_t)(hh * 32 + lq)) * SLEN + kt + f * 16 + hi * 8);

        // ---- online softmax, fully in-register (scores in exp2 domain) ----
        float pm[8];
#pragma unroll
        for (int c = 0; c < 4; ++c) {
            pm[c]     = fmaxf(fmaxf(s0[4 * c], s0[4 * c + 1]), fmaxf(s0[4 * c + 2], s0[4 * c + 3]));
            pm[c + 4] = fmaxf(fmaxf(s1[4 * c], s1[4 * c + 1]), fmaxf(s1[4 * c + 2], s1[4 * c + 3]));
        }
        float tmax = fmaxf(fmaxf(fmaxf(pm[0], pm[1]), fmaxf(pm[2], pm[3])),
                           fmaxf(fmaxf(pm[4], pm[5]), fmaxf(pm[6], pm[7])));
        tmax = fmaxf(tmax, __shfl_xor(tmax, 32));

        // defer-max (T13): only rescale when the max grew by > 8 (exp2 domain)
        if (!__all(tmax <= m_run + 8.0f)) {
            float mn = fmaxf(m_run, tmax);
            float corr = fast_exp2(m_run - mn);
#pragma unroll
            for (int r = 0; r < 16; ++r) { oA[r] *= corr; oB[r] *= corr; }
            l_run *= corr;
            m_run = mn;
        }

#pragma unroll
        for (int r = 0; r < 16; ++r) {
            s0[r] = fast_exp2(s0[r] - m_run);
            s1[r] = fast_exp2(s1[r] - m_run);
        }
        float ps[8];
#pragma unroll
        for (int c = 0; c < 4; ++c) {
            ps[c]     = (s0[4 * c] + s0[4 * c + 1]) + (s0[4 * c + 2] + s0[4 * c + 3]);
            ps[c + 4] = (s1[4 * c] + s1[4 * c + 1]) + (s1[4 * c + 2] + s1[4 * c + 3]);
        }
        float tsum = ((ps[0] + ps[1]) + (ps[2] + ps[3])) + ((ps[4] + ps[5]) + (ps[6] + ps[7]));
        tsum += __shfl_xor(tsum, 32);
        l_run += tsum;

        // ---- P (f32, D-layout) -> bf16 A-fragments via cvt_pk + permlane32_swap
        bf16x8 pa[4];
#pragma unroll
        for (int f = 0; f < 4; ++f) {
            const f32x16 S = (f < 2) ? s0 : s1;
            const int b = (f & 1) * 8;
            unsigned a0 = cvtpk(S[b + 0], S[b + 1]);
            unsigned b0 = cvtpk(S[b + 4], S[b + 5]);
            permswap(a0, b0);
            unsigned a1 = cvtpk(S[b + 2], S[b + 3]);
            unsigned b1 = cvtpk(S[b + 6], S[b + 7]);
            permswap(a1, b1);
            u32x4 t = {a0, a1, b0, b1};
            pa[f] = __builtin_bit_cast(bf16x8, t);
        }

        // ---- PV (swapped): A = V^T (rows=d), B = P^T (cols=q) ----
#pragma unroll
        for (int f = 0; f < 4; ++f) {
            oA = __builtin_amdgcn_mfma_f32_32x32x16_bf16(vf[0][f], pa[f], oA, 0, 0, 0);
            oB = __builtin_amdgcn_mfma_f32_32x32x16_bf16(vf[1][f], pa[f], oB, 0, 0, 0);
        }
    }

    // ---- epilogue: normalize, store fp32 ----
    const float inv = 1.0f / l_run;
    float* dst = out + ((size_t)(n * SLEN + q0 + lq)) * DMODEL + h * DH;
#pragma unroll
    for (int grp = 0; grp < 4; ++grp) {
        float4 stA, stB;
        stA.x = oA[4 * grp + 0] * inv; stA.y = oA[4 * grp + 1] * inv;
        stA.z = oA[4 * grp + 2] * inv; stA.w = oA[4 * grp + 3] * inv;
        stB.x = oB[4 * grp + 0] * inv; stB.y = oB[4 * grp + 1] * inv;
        stB.z = oB[4 * grp + 2] * inv; stB.w = oB[4 * grp + 3] * inv;
        *reinterpret_cast<float4*>(dst + grp * 8 + hi * 4)      = stA;
        *reinterpret_cast<float4*>(dst + 32 + grp * 8 + hi * 4) = stB;
    }
}

extern "C" void kernel_launch(void* const* d_in, const int* in_sizes, int n_in,
                              void* d_out, int out_size, void* d_ws, size_t ws_size,
                              hipStream_t stream) {
    const float* seq = (const float*)d_in[0];
    const float* Wq  = (const float*)d_in[1];
    const float* bq  = (const float*)d_in[2];
    const float* Wk  = (const float*)d_in[3];
    const float* bk  = (const float*)d_in[4];
    const float* Wv  = (const float*)d_in[5];
    const float* bv  = (const float*)d_in[6];

    const size_t per_tensor = (size_t)NB * NH * SLEN * DH;
    unsigned short* Qb = (unsigned short*)d_ws;
    unsigned short* Kb = Qb + per_tensor;
    unsigned short* Vt = Kb + per_tensor;

    qkv_proj_kernel<<<dim3(NB * NH * (SLEN / 64)), dim3(256), 0, stream>>>(
        seq, Wq, bq, Wk, bk, Wv, bv, Qb, Kb, Vt);
    attn_kernel<<<dim3(NB * NH * (SLEN / 128)), dim3(256), 0, stream>>>(
        Qb, Kb, Vt, (float*)d_out);
}